// Round 10
// baseline (1965.748 us; speedup 1.0000x reference)
//
#include <hip/hip_runtime.h>

using u64 = unsigned long long;

// ---------------------------------------------------------------------------
// CIFAR10 BinaryNet, f32-faithful edition (R10: occupancy + coalesced bin2d).
// Correctness contract (R4-R9 passed absmax 0.0): replicate the np-f32
// reference bit-exactly where signs are decided:
//  * bin_act/bin_w literally: rint(clip((x+1)*0.5,0,1)) != 0, f32, half-even
//  * conv1: f32 accumulation in (ci,ky,kx) sequential order + bias in f32,
//    LDS-staged image with zero halo, fmaf(+-1.0f,x,acc) == +-x add rounding
//  * binary layers: exact integer dot (XOR+POPCNT), order-independent
//  * BN mean/var: numpy reduction replicated (inner pairwise 8-acc blocks of
//    128 -> r[j] sequential over i then 8-way tree; outer axes sequential);
//    bn chain ((x-m)*rsqrt)*g+be in f32
// R10: (1) conv_bin NWAVES per-variant launch_bounds: CQ=2 -> 8 waves/EU
// (VGPR 52 fits 64 cap), CQ=4 -> 6, CQ=8 -> 4 (spill-safe). R9 showed
// VALUBusy 86% at Occupancy 40%. (2) bin2d: lane = position, loop channels,
// per-lane word assembly -> coalesced 128B loads instead of 64-line gathers.
// Same math/bit-map/addresses => bit-exact.
// Activations packed [n][h][w][C/64] u64, bit c%64 of word c/64 == (+1).
// ---------------------------------------------------------------------------

// literal bin_act / bin_w: returns 1 for +1, 0 for -1
__device__ __forceinline__ int bin01(float x) {
  float u = (x + 1.0f) * 0.5f;
  u = fminf(fmaxf(u, 0.0f), 1.0f);
  return rintf(u) != 0.0f;  // round half-even, tie -> 0 -> -1
}

// ============================ weight packing ===============================
__global__ void pack_conv_w(const float* __restrict__ w, u64* __restrict__ out,
                            int Cout, int Cin) {
  const int cqn = Cin >> 6;
  const int total = Cout * 9 * cqn;
  const int idx = blockIdx.x * 256 + threadIdx.x;
  if (idx >= total) return;
  int r = idx;
  const int q = r % cqn; r /= cqn;
  const int kx = r % 3; r /= 3;
  const int ky = r % 3;
  const int co = r / 3;
  u64 word = 0;
  for (int l = 0; l < 64; ++l) {
    const int ci = q * 64 + l;
    if (bin01(w[((size_t)(co * Cin + ci) * 3 + ky) * 3 + kx])) word |= (1ull << l);
  }
  out[idx] = word;
}

__global__ void pack_fc_w(const float* __restrict__ w, u64* __restrict__ out,
                          int Fi, int Fo) {
  const int fiq = Fi >> 6;
  const int total = Fo * fiq;
  const int idx = blockIdx.x * 256 + threadIdx.x;
  if (idx >= total) return;
  const int q = idx % fiq, o = idx / fiq;
  u64 word = 0;
  for (int l = 0; l < 64; ++l)
    if (bin01(w[(size_t)o * Fi + q * 64 + l])) word |= (1ull << l);
  out[idx] = word;
}

// fc1 with NCHW-flatten permutation: f = c*16 + h*4 + w; act word q=(h*4+w)*8+cq
__global__ void pack_fc1_w(const float* __restrict__ w, u64* __restrict__ out) {
  const int idx = blockIdx.x * 256 + threadIdx.x;  // 1024*128
  const int o = idx >> 7, q = idx & 127;
  const int hw = q >> 3, cq = q & 7;
  u64 word = 0;
  for (int l = 0; l < 64; ++l) {
    const int f = (cq * 64 + l) * 16 + hw;
    if (bin01(w[(size_t)o * 8192 + f])) word |= (1ull << l);
  }
  out[idx] = word;
}

// conv1 weight signs as +-1.0f floats (k = ci*9+dy*3+dx), for uniform s_load
__global__ void pack_w1f(const float* __restrict__ w1, float* __restrict__ w1f) {
  const int i = blockIdx.x * 256 + threadIdx.x;  // 3456
  if (i < 3456) w1f[i] = bin01(w1[i]) ? 1.0f : -1.0f;
}

// ============================== conv1 (f32) ================================
__device__ __forceinline__ void stage_image(const float* __restrict__ x, int n,
                                            float* __restrict__ xs, int nthreads,
                                            int t) {
  for (int idx = t; idx < 3 * 34 * 34; idx += nthreads) {
    const int ci = idx / 1156, rem = idx % 1156;
    const int hy = rem / 34, wx = rem % 34;
    float v = 0.0f;
    if (hy >= 1 && hy <= 32 && wx >= 1 && wx <= 32)
      v = x[(size_t)n * 3072 + ci * 1024 + (hy - 1) * 32 + (wx - 1)];
    xs[idx] = v;
  }
}

// eval + leaf-sum kernel. block = (n, quarter q); thread = position p (256).
template <int PASS>
__global__ void conv1_eval(const float* __restrict__ x,
                           const float* __restrict__ w1f,
                           const float* __restrict__ cb,
                           const float* __restrict__ st,
                           float* __restrict__ BL) {
  const int blk = blockIdx.x;  // n*4 + q
  const int n = blk >> 2, q = blk & 3;
  const int t = threadIdx.x;   // 256
  __shared__ float xs[3 * 34 * 34];
  __shared__ float yl[256 * 8];    // [p][j8]
  __shared__ float rl[2 * 8 * 8];  // [L][c8][j]
  stage_image(x, n, xs, 256, t);
  __syncthreads();
  const int hw = q * 256 + t;
  const int h = hw >> 5, w = hw & 31;
  float win[27];
#pragma unroll
  for (int k = 0; k < 27; ++k) {
    const int ci = k / 9, dy = (k % 9) / 3, dx = k % 3;
    win[k] = xs[ci * 1156 + (h + dy) * 34 + (w + dx)];
  }
  for (int cc = 0; cc < 16; ++cc) {  // 8 channels per chunk
    float y8[8];
#pragma unroll
    for (int j8 = 0; j8 < 8; ++j8) {
      const int c = cc * 8 + j8;
      const float* wp = w1f + c * 27;
      float acc = 0.0f;
#pragma unroll
      for (int k = 0; k < 27; ++k) acc = fmaf(wp[k], win[k], acc);
      float y = acc + cb[c];
      if (PASS) { const float d = y - st[2 * c]; y = d * d; }
      y8[j8] = y;
    }
    __syncthreads();  // previous chunk's readers done
#pragma unroll
    for (int j8 = 0; j8 < 8; ++j8) yl[t * 8 + j8] = y8[j8];
    __syncthreads();
    if (t < 128) {  // numpy 8-accumulator pass: r = sum_i y[i*8+j], i sequential
      const int L = t >> 6, j = (t >> 3) & 7, c8 = t & 7;
      float r = yl[(L * 128 + j) * 8 + c8];
      for (int i = 1; i < 16; ++i) r += yl[(L * 128 + i * 8 + j) * 8 + c8];
      rl[(L * 8 + c8) * 8 + j] = r;
    }
    __syncthreads();
    if (t < 16) {  // 8-way tree combine, write leaf sum
      const int L = t >> 3, c8 = t & 7;
      const float* p = rl + (L * 8 + c8) * 8;
      const float s =
          ((p[0] + p[1]) + (p[2] + p[3])) + ((p[4] + p[5]) + (p[6] + p[7]));
      BL[((size_t)(n * 8) + (q * 2 + L)) * 128 + (cc * 8 + c8)] = s;
    }
  }
}

// leaf-pairwise then batch-sequential combine (numpy multi-axis reduce order)
__global__ void conv1_comb2(const float* __restrict__ BL, float* __restrict__ st,
                            int pass) {
  const int c = threadIdx.x;  // 128
  if (c >= 128) return;
  float S = 0.0f;
  for (int n = 0; n < 256; ++n) {
    const float* L = BL + (size_t)n * 1024;
    const float l0 = L[0 * 128 + c], l1 = L[1 * 128 + c], l2 = L[2 * 128 + c],
                l3 = L[3 * 128 + c], l4 = L[4 * 128 + c], l5 = L[5 * 128 + c],
                l6 = L[6 * 128 + c], l7 = L[7 * 128 + c];
    const float Ln = ((l0 + l1) + (l2 + l3)) + ((l4 + l5) + (l6 + l7));
    S = (n == 0) ? Ln : (S + Ln);
  }
  if (pass == 0) st[2 * c] = S / 262144.0f;
  else           st[2 * c + 1] = 1.0f / sqrtf(S / 262144.0f + 1e-4f);
}

// binarize: thread = position; loops all 128 channels with register window,
// packs bits per-thread (bit l of word cq <-> c = cq*64+l).
__global__ void conv1_binz(const float* __restrict__ x,
                           const float* __restrict__ w1f,
                           const float* __restrict__ cb,
                           const float* __restrict__ st,
                           const float* __restrict__ g,
                           const float* __restrict__ be,
                           u64* __restrict__ out) {
  const int blk = blockIdx.x;  // n*4 + q
  const int n = blk >> 2, q = blk & 3;
  const int t = threadIdx.x;   // 256
  __shared__ float xs[3 * 34 * 34];
  stage_image(x, n, xs, 256, t);
  __syncthreads();
  const int hw = q * 256 + t;
  const int h = hw >> 5, w = hw & 31;
  float win[27];
#pragma unroll
  for (int k = 0; k < 27; ++k) {
    const int ci = k / 9, dy = (k % 9) / 3, dx = k % 3;
    win[k] = xs[ci * 1156 + (h + dy) * 34 + (w + dx)];
  }
  u64 m0 = 0, m1 = 0;
  for (int c = 0; c < 128; ++c) {
    const float* wp = w1f + c * 27;
    float acc = 0.0f;
#pragma unroll
    for (int k = 0; k < 27; ++k) acc = fmaf(wp[k], win[k], acc);
    const float y = acc + cb[c];
    const float tv = ((y - st[2 * c]) * st[2 * c + 1]) * g[c] + be[c];
    const u64 bit = (u64)bin01(tv);
    if (c < 64) m0 |= bit << c;
    else        m1 |= bit << (c - 64);
  }
  u64* dst = out + ((size_t)(n * 1024 + hw)) * 2;
  dst[0] = m0;
  dst[1] = m1;
}

// ===================== binary conv (+optional maxpool) =====================
// tap-major (R8): per tap, stage NE x QC cell-words in registers, reuse across
// NCPB channels; pc[NCPB][NE] persists. NW = min waves/EU (R10 per-variant).
template <int CQ, int POOL, int H, int COUT, int NCPB, int NW>
__launch_bounds__(256, NW)
__global__ void conv_bin(const u64* __restrict__ xin, const u64* __restrict__ wpk,
                         short* __restrict__ pre) {
  constexpr int OH = H / POOL;
  constexpr int PLANE = OH * OH;
  constexpr int G = 256 / PLANE;
  constexpr int NE = POOL * POOL;
  constexpr int NW_ = H * H * CQ;
  constexpr int QC = (CQ > 4) ? 4 : CQ;
  constexpr int NQC = CQ / QC;
  const int n = blockIdx.x;
  const int t = threadIdx.x;
  __shared__ u64 xs[NW_];
  const u64* src = xin + (size_t)n * NW_;
  for (int i = t; i < NW_; i += 256) xs[i] = src[i];
  __syncthreads();
  const int cosub = t / PLANE;
  const int pos = t % PLANE;
  const int oh = pos / OH, ow = pos % OH;

  int pc[NCPB][NE];
#pragma unroll
  for (int cc = 0; cc < NCPB; ++cc)
#pragma unroll
    for (int e = 0; e < NE; ++e) pc[cc][e] = 0;

#pragma unroll
  for (int qc = 0; qc < NQC; ++qc) {
#pragma unroll
    for (int k = 0; k < 9; ++k) {
      const int dy = k / 3, dx = k % 3;
      u64 cw[NE][QC];
      bool cv[NE];
#pragma unroll
      for (int py = 0; py < POOL; ++py) {
#pragma unroll
        for (int px = 0; px < POOL; ++px) {
          const int hh = oh * POOL + py + dy - 1;
          const int ww = ow * POOL + px + dx - 1;
          const bool v = ((unsigned)hh < (unsigned)H) && ((unsigned)ww < (unsigned)H);
          const int e = py * POOL + px;
          cv[e] = v;
          const int base = v ? ((hh * H + ww) * CQ + qc * QC) : 0;
#pragma unroll
          for (int q = 0; q < QC; ++q) cw[e][q] = xs[base + q];
        }
      }
#pragma unroll
      for (int cc = 0; cc < NCPB; ++cc) {
        const int co = (blockIdx.y * NCPB + cc) * G + cosub;
        const u64* wp = wpk + ((size_t)co * 9 + k) * CQ + qc * QC;
        u64 w[QC];
#pragma unroll
        for (int q = 0; q < QC; ++q) w[q] = wp[q];
#pragma unroll
        for (int e = 0; e < NE; ++e) {
          int tp = 0;
#pragma unroll
          for (int q = 0; q < QC; ++q) tp += __popcll(cw[e][q] ^ w[q]);
          pc[cc][e] += cv[e] ? tp : 0;
        }
      }
    }
  }

  int vcnt[NE];
#pragma unroll
  for (int py = 0; py < POOL; ++py) {
#pragma unroll
    for (int px = 0; px < POOL; ++px) {
      int cvn = 0;
#pragma unroll
      for (int dy = 0; dy < 3; ++dy)
#pragma unroll
        for (int dx = 0; dx < 3; ++dx) {
          const int hh = oh * POOL + py + dy - 1, ww = ow * POOL + px + dx - 1;
          cvn += (((unsigned)hh < (unsigned)H) && ((unsigned)ww < (unsigned)H)) ? 1 : 0;
        }
      vcnt[py * POOL + px] = cvn;
    }
  }
#pragma unroll
  for (int cc = 0; cc < NCPB; ++cc) {
    const int co = (blockIdx.y * NCPB + cc) * G + cosub;
    int best = -1000000;
#pragma unroll
    for (int e = 0; e < NE; ++e) {
      const int dot = vcnt[e] * (CQ * 64) - 2 * pc[cc][e];
      best = dot > best ? dot : best;
    }
    pre[((size_t)(n * COUT + co) * OH + oh) * OH + ow] = (short)best;
  }
}

// ======================= BN stats, numpy-faithful ==========================
template <int PASS>
__device__ __forceinline__ float acc8(const short* __restrict__ p, float b, float m,
                                      int start, int len) {
  float r[8];
#pragma unroll
  for (int j = 0; j < 8; ++j) {
    float y = (float)p[start + j] + b;
    if (PASS) { const float d = y - m; y = d * d; }
    r[j] = y;
  }
  for (int i = 8; i < len; i += 8) {
#pragma unroll
    for (int j = 0; j < 8; ++j) {
      float y = (float)p[start + i + j] + b;
      if (PASS) { const float d = y - m; y = d * d; }
      r[j] += y;
    }
  }
  return ((r[0] + r[1]) + (r[2] + r[3])) + ((r[4] + r[5]) + (r[6] + r[7]));
}

template <int PASS>
__device__ __forceinline__ float np_sum_hw(const short* __restrict__ p, float b,
                                           float m, int HW) {
  if (HW == 256) return acc8<PASS>(p, b, m, 0, 128) + acc8<PASS>(p, b, m, 128, 128);
  return acc8<PASS>(p, b, m, 0, HW);  // HW = 16 or 64
}

template <int HW>
__global__ void conv_stats(const short* __restrict__ pre, const float* __restrict__ cb,
                           float* __restrict__ st, int Cout) {
  const int c = blockIdx.x;
  const int n = threadIdx.x;  // 256
  const float b = cb[c];
  const short* p = pre + ((size_t)n * Cout + c) * HW;
  __shared__ float ls[256];
  ls[n] = np_sum_hw<0>(p, b, 0.0f, HW);
  __syncthreads();
  __shared__ float ms;
  if (n == 0) {
    float S = ls[0];
    for (int i = 1; i < 256; ++i) S += ls[i];
    ms = S / (float)(256 * HW);
  }
  __syncthreads();
  const float m = ms;
  __syncthreads();
  ls[n] = np_sum_hw<1>(p, b, m, HW);
  __syncthreads();
  if (n == 0) {
    float S = ls[0];
    for (int i = 1; i < 256; ++i) S += ls[i];
    const float v = S / (float)(256 * HW);
    st[2 * c] = m;
    st[2 * c + 1] = 1.0f / sqrtf(v + 1e-4f);
  }
}

// =========================== binarize 2d / pack ============================
// R10: lane = spatial position, loop channels, per-lane u64 assembly.
// Loads coalesced (fixed c: adjacent lanes read adjacent shorts). Same f32
// expression, same bit<->channel map (bit c of word cq <-> ch=cq*64+c), same
// output addresses as the old ballot version => bit-exact.
__global__ void bin2d(const short* __restrict__ pre, const float* __restrict__ st,
                      const float* __restrict__ cb, const float* __restrict__ g,
                      const float* __restrict__ be, u64* __restrict__ out,
                      int Cout, int OH) {
  const int CQ = Cout >> 6;
  const int HW = OH * OH;
  const int widx = blockIdx.x * 256 + threadIdx.x;  // (n*CQ+cq)*HW+hw
  const int hw = widx % HW;
  const int r = widx / HW;
  const int cq = r % CQ;
  const int n = r / CQ;
  const short* p = pre + ((size_t)(n * Cout + cq * 64)) * HW + hw;
  u64 mask = 0;
  for (int c = 0; c < 64; ++c) {
    const int ch = cq * 64 + c;
    const float val = (float)p[(size_t)c * HW] + cb[ch];
    const float tv = ((val - st[2 * ch]) * st[2 * ch + 1]) * g[ch] + be[ch];
    mask |= ((u64)bin01(tv)) << c;
  }
  out[((size_t)n * HW + hw) * CQ + cq] = mask;
}

// ================================ fc layers ================================
__global__ void fc_layer(const u64* __restrict__ xin, const u64* __restrict__ wpk,
                         short* __restrict__ pre, int FiQ, int Fo) {
  const int o = blockIdx.x;
  const int n = threadIdx.x;  // 256
  const u64* xp = xin + (size_t)n * FiQ;
  const u64* wp = wpk + (size_t)o * FiQ;
  int pc = 0;
  for (int q = 0; q < FiQ; ++q) pc += __popcll(xp[q] ^ wp[q]);
  pre[(size_t)n * Fo + o] = (short)(FiQ * 64 - 2 * pc);
}

__global__ void fc_stats(const short* __restrict__ pre, const float* __restrict__ fb,
                         float* __restrict__ st, int Fo) {
  const int o = blockIdx.x * 256 + threadIdx.x;
  if (o >= Fo) return;
  const float b = fb[o];
  float S = (float)pre[o] + b;
  for (int n = 1; n < 256; ++n) S += (float)pre[(size_t)n * Fo + o] + b;
  const float m = S / 256.0f;
  float d0 = (float)pre[o] + b - m;
  float V = d0 * d0;
  for (int n = 1; n < 256; ++n) {
    const float d = (float)pre[(size_t)n * Fo + o] + b - m;
    V += d * d;
  }
  st[2 * o] = m;
  st[2 * o + 1] = 1.0f / sqrtf(V / 256.0f + 1e-4f);
}

__global__ void fc_bin(const short* __restrict__ pre, const float* __restrict__ st,
                       const float* __restrict__ fb, const float* __restrict__ g,
                       const float* __restrict__ be, u64* __restrict__ out, int Fo) {
  const int gid = blockIdx.x * 4 + (threadIdx.x >> 6);
  const int lane = threadIdx.x & 63;
  const int OQ = Fo >> 6;
  const int oq = gid % OQ, n = gid / OQ;
  const int o = oq * 64 + lane;
  const float val = (float)pre[(size_t)n * Fo + o] + fb[o];
  const float tv = ((val - st[2 * o]) * st[2 * o + 1]) * g[o] + be[o];
  const u64 mask = __ballot(bin01(tv));
  if (lane == 0) out[(size_t)n * OQ + oq] = mask;
}

__global__ void fc_out(const short* __restrict__ pre, const float* __restrict__ st,
                       const float* __restrict__ fb, const float* __restrict__ g,
                       const float* __restrict__ be, float* __restrict__ out) {
  const int i = blockIdx.x * 256 + threadIdx.x;  // 2560
  if (i >= 2560) return;
  const int o = i % 10;
  const float val = (float)pre[i] + fb[o];
  out[i] = ((val - st[2 * o]) * st[2 * o + 1]) * g[o] + be[o];
}

// ================================= launch ==================================
extern "C" void kernel_launch(void* const* d_in, const int* in_sizes, int n_in,
                              void* d_out, int out_size, void* d_ws, size_t ws_size,
                              hipStream_t stream) {
  if (n_in < 37) return;
  const float* x = (const float*)d_in[0];
  const float *cw1 = (const float*)d_in[1],  *cb1 = (const float*)d_in[2],  *g1 = (const float*)d_in[3],  *be1 = (const float*)d_in[4];
  const float *cw2 = (const float*)d_in[5],  *cb2 = (const float*)d_in[6],  *g2 = (const float*)d_in[7],  *be2 = (const float*)d_in[8];
  const float *cw3 = (const float*)d_in[9],  *cb3 = (const float*)d_in[10], *g3 = (const float*)d_in[11], *be3 = (const float*)d_in[12];
  const float *cw4 = (const float*)d_in[13], *cb4 = (const float*)d_in[14], *g4 = (const float*)d_in[15], *be4 = (const float*)d_in[16];
  const float *cw5 = (const float*)d_in[17], *cb5 = (const float*)d_in[18], *g5 = (const float*)d_in[19], *be5 = (const float*)d_in[20];
  const float *cw6 = (const float*)d_in[21], *cb6 = (const float*)d_in[22], *g6 = (const float*)d_in[23], *be6 = (const float*)d_in[24];
  const float *fw1 = (const float*)d_in[25], *fb1 = (const float*)d_in[26], *gf1 = (const float*)d_in[27], *bef1 = (const float*)d_in[28];
  const float *fw2 = (const float*)d_in[29], *fb2 = (const float*)d_in[30], *gf2 = (const float*)d_in[31], *bef2 = (const float*)d_in[32];
  const float *fw3 = (const float*)d_in[33], *fb3 = (const float*)d_in[34], *gf3 = (const float*)d_in[35], *bef3 = (const float*)d_in[36];
  float* out = (float*)d_out;

  char* ws = (char*)d_ws;
  if (ws_size < 46137344) return;
  float* ST = (float*)ws;                    // f32 stats (m, 1/sqrt(v+eps)) pairs
  float* W1F = (float*)(ws + 32768);         // conv1 +-1.0f signs, 13824 B
  float* BL = (float*)(ws + 65536);          // conv1 leaf partials [256][8][128], 1 MB
  u64* W = (u64*)(ws + 1179648);             // packed weights, 1752320 B
  u64* A = (u64*)(ws + 2981888);             // packed activations, 9240576 B
  short* PRE = (short*)(ws + 12582912);      // integer pre-activations (reused)
  const int S1 = 0, S2 = 256, S3 = 512, S4 = 1024, S5 = 1536, S6 = 2560;
  const int SF1 = 3584, SF2 = 5632, SF3 = 7680;
  const size_t WC2 = 0, WC3 = 2304, WC4 = 6912, WC5 = 16128, WC6 = 34560;
  const size_t WF1 = 71424, WF2 = 202496, WF3 = 218880;
  const size_t A1 = 0, A2 = 524288, A3 = 655360, A4 = 917504, A5 = 983040;
  const size_t A6 = 1114112, AF1 = 1146880, AF2 = 1150976;

  // pack weights (literal bin_w semantics)
  pack_w1f<<<14, 256, 0, stream>>>(cw1, W1F);
  pack_conv_w<<<9, 256, 0, stream>>>(cw2, W + WC2, 128, 128);
  pack_conv_w<<<18, 256, 0, stream>>>(cw3, W + WC3, 256, 128);
  pack_conv_w<<<36, 256, 0, stream>>>(cw4, W + WC4, 256, 256);
  pack_conv_w<<<72, 256, 0, stream>>>(cw5, W + WC5, 512, 256);
  pack_conv_w<<<144, 256, 0, stream>>>(cw6, W + WC6, 512, 512);
  pack_fc1_w<<<512, 256, 0, stream>>>(fw1, W + WF1);
  pack_fc_w<<<64, 256, 0, stream>>>(fw2, W + WF2, 1024, 1024);
  pack_fc_w<<<1, 256, 0, stream>>>(fw3, W + WF3, 1024, 10);

  // layer 1: position-major f32 conv, numpy-faithful stats, binarize
  conv1_eval<0><<<1024, 256, 0, stream>>>(x, W1F, cb1, ST + S1, BL);
  conv1_comb2<<<1, 128, 0, stream>>>(BL, ST + S1, 0);
  conv1_eval<1><<<1024, 256, 0, stream>>>(x, W1F, cb1, ST + S1, BL);
  conv1_comb2<<<1, 128, 0, stream>>>(BL, ST + S1, 1);
  conv1_binz<<<1024, 256, 0, stream>>>(x, W1F, cb1, ST + S1, g1, be1, A + A1);

  // binary conv stack (tap-major, channel-split grids, per-variant NW)
  conv_bin<2, 2, 32, 128, 4, 8><<<dim3(256, 32), 256, 0, stream>>>(A + A1, W + WC2, PRE);
  conv_stats<256><<<128, 256, 0, stream>>>(PRE, cb2, ST + S2, 128);
  bin2d<<<512, 256, 0, stream>>>(PRE, ST + S2, cb2, g2, be2, A + A2, 128, 16);

  conv_bin<2, 1, 16, 256, 8, 8><<<dim3(256, 32), 256, 0, stream>>>(A + A2, W + WC3, PRE);
  conv_stats<256><<<256, 256, 0, stream>>>(PRE, cb3, ST + S3, 256);
  bin2d<<<1024, 256, 0, stream>>>(PRE, ST + S3, cb3, g3, be3, A + A3, 256, 16);

  conv_bin<4, 2, 16, 256, 4, 6><<<dim3(256, 16), 256, 0, stream>>>(A + A3, W + WC4, PRE);
  conv_stats<64><<<256, 256, 0, stream>>>(PRE, cb4, ST + S4, 256);
  bin2d<<<256, 256, 0, stream>>>(PRE, ST + S4, cb4, g4, be4, A + A4, 256, 8);

  conv_bin<4, 1, 8, 512, 8, 8><<<dim3(256, 16), 256, 0, stream>>>(A + A4, W + WC5, PRE);
  conv_stats<64><<<512, 256, 0, stream>>>(PRE, cb5, ST + S5, 512);
  bin2d<<<512, 256, 0, stream>>>(PRE, ST + S5, cb5, g5, be5, A + A5, 512, 8);

  conv_bin<8, 2, 8, 512, 2, 4><<<dim3(256, 16), 256, 0, stream>>>(A + A5, W + WC6, PRE);
  conv_stats<16><<<512, 256, 0, stream>>>(PRE, cb6, ST + S6, 512);
  bin2d<<<128, 256, 0, stream>>>(PRE, ST + S6, cb6, g6, be6, A + A6, 512, 4);

  // fc stack
  fc_layer<<<1024, 256, 0, stream>>>(A + A6, W + WF1, PRE, 128, 1024);
  fc_stats<<<4, 256, 0, stream>>>(PRE, fb1, ST + SF1, 1024);
  fc_bin<<<1024, 256, 0, stream>>>(PRE, ST + SF1, fb1, gf1, bef1, A + AF1, 1024);

  fc_layer<<<1024, 256, 0, stream>>>(A + AF1, W + WF2, PRE, 16, 1024);
  fc_stats<<<4, 256, 0, stream>>>(PRE, fb2, ST + SF2, 1024);
  fc_bin<<<1024, 256, 0, stream>>>(PRE, ST + SF2, fb2, gf2, bef2, A + AF2, 1024);

  fc_layer<<<10, 256, 0, stream>>>(A + AF2, W + WF3, PRE, 16, 10);
  fc_stats<<<1, 256, 0, stream>>>(PRE, fb3, ST + SF3, 10);
  fc_out<<<10, 256, 0, stream>>>(PRE, ST + SF3, fb3, gf3, bef3, out);
}

// Round 11
// 1137.836 us; speedup vs baseline: 1.7276x; 1.7276x over previous
//
#include <hip/hip_runtime.h>

using u64 = unsigned long long;

// ---------------------------------------------------------------------------
// CIFAR10 BinaryNet, f32-faithful edition (R11: revert NW to 4, keep bin2d).
// Correctness contract (R4-R10 passed absmax 0.0): replicate the np-f32
// reference bit-exactly where signs are decided:
//  * bin_act/bin_w literally: rint(clip((x+1)*0.5,0,1)) != 0, f32, half-even
//  * conv1: f32 accumulation in (ci,ky,kx) sequential order + bias in f32,
//    LDS-staged image with zero halo, fmaf(+-1.0f,x,acc) == +-x add rounding
//  * binary layers: exact integer dot (XOR+POPCNT), order-independent
//  * BN mean/var: numpy reduction replicated (inner pairwise 8-acc blocks of
//    128 -> r[j] sequential over i then 8-way tree; outer axes sequential);
//    bn chain ((x-m)*rsqrt)*g+be in f32
// R11: R10's NW=8/6 launch bounds made the allocator spill (VGPR 52 -> 32,
// FETCH 483 MB, WRITE 983 MB, +700 us). LESSON (3rd occurrence): this kernel
// family spills under any bound tighter than (256,4). Reverted all conv_bin
// to NW=4 (R9-identical, 52 VGPR, no spill). Kept R10's coalesced bin2d
// (lane = position, loop channels, per-lane u64 assembly - strictly better
// pattern, not implicated in the regression).
// Activations packed [n][h][w][C/64] u64, bit c%64 of word c/64 == (+1).
// ---------------------------------------------------------------------------

// literal bin_act / bin_w: returns 1 for +1, 0 for -1
__device__ __forceinline__ int bin01(float x) {
  float u = (x + 1.0f) * 0.5f;
  u = fminf(fmaxf(u, 0.0f), 1.0f);
  return rintf(u) != 0.0f;  // round half-even, tie -> 0 -> -1
}

// ============================ weight packing ===============================
__global__ void pack_conv_w(const float* __restrict__ w, u64* __restrict__ out,
                            int Cout, int Cin) {
  const int cqn = Cin >> 6;
  const int total = Cout * 9 * cqn;
  const int idx = blockIdx.x * 256 + threadIdx.x;
  if (idx >= total) return;
  int r = idx;
  const int q = r % cqn; r /= cqn;
  const int kx = r % 3; r /= 3;
  const int ky = r % 3;
  const int co = r / 3;
  u64 word = 0;
  for (int l = 0; l < 64; ++l) {
    const int ci = q * 64 + l;
    if (bin01(w[((size_t)(co * Cin + ci) * 3 + ky) * 3 + kx])) word |= (1ull << l);
  }
  out[idx] = word;
}

__global__ void pack_fc_w(const float* __restrict__ w, u64* __restrict__ out,
                          int Fi, int Fo) {
  const int fiq = Fi >> 6;
  const int total = Fo * fiq;
  const int idx = blockIdx.x * 256 + threadIdx.x;
  if (idx >= total) return;
  const int q = idx % fiq, o = idx / fiq;
  u64 word = 0;
  for (int l = 0; l < 64; ++l)
    if (bin01(w[(size_t)o * Fi + q * 64 + l])) word |= (1ull << l);
  out[idx] = word;
}

// fc1 with NCHW-flatten permutation: f = c*16 + h*4 + w; act word q=(h*4+w)*8+cq
__global__ void pack_fc1_w(const float* __restrict__ w, u64* __restrict__ out) {
  const int idx = blockIdx.x * 256 + threadIdx.x;  // 1024*128
  const int o = idx >> 7, q = idx & 127;
  const int hw = q >> 3, cq = q & 7;
  u64 word = 0;
  for (int l = 0; l < 64; ++l) {
    const int f = (cq * 64 + l) * 16 + hw;
    if (bin01(w[(size_t)o * 8192 + f])) word |= (1ull << l);
  }
  out[idx] = word;
}

// conv1 weight signs as +-1.0f floats (k = ci*9+dy*3+dx), for uniform s_load
__global__ void pack_w1f(const float* __restrict__ w1, float* __restrict__ w1f) {
  const int i = blockIdx.x * 256 + threadIdx.x;  // 3456
  if (i < 3456) w1f[i] = bin01(w1[i]) ? 1.0f : -1.0f;
}

// ============================== conv1 (f32) ================================
__device__ __forceinline__ void stage_image(const float* __restrict__ x, int n,
                                            float* __restrict__ xs, int nthreads,
                                            int t) {
  for (int idx = t; idx < 3 * 34 * 34; idx += nthreads) {
    const int ci = idx / 1156, rem = idx % 1156;
    const int hy = rem / 34, wx = rem % 34;
    float v = 0.0f;
    if (hy >= 1 && hy <= 32 && wx >= 1 && wx <= 32)
      v = x[(size_t)n * 3072 + ci * 1024 + (hy - 1) * 32 + (wx - 1)];
    xs[idx] = v;
  }
}

// eval + leaf-sum kernel. block = (n, quarter q); thread = position p (256).
template <int PASS>
__global__ void conv1_eval(const float* __restrict__ x,
                           const float* __restrict__ w1f,
                           const float* __restrict__ cb,
                           const float* __restrict__ st,
                           float* __restrict__ BL) {
  const int blk = blockIdx.x;  // n*4 + q
  const int n = blk >> 2, q = blk & 3;
  const int t = threadIdx.x;   // 256
  __shared__ float xs[3 * 34 * 34];
  __shared__ float yl[256 * 8];    // [p][j8]
  __shared__ float rl[2 * 8 * 8];  // [L][c8][j]
  stage_image(x, n, xs, 256, t);
  __syncthreads();
  const int hw = q * 256 + t;
  const int h = hw >> 5, w = hw & 31;
  float win[27];
#pragma unroll
  for (int k = 0; k < 27; ++k) {
    const int ci = k / 9, dy = (k % 9) / 3, dx = k % 3;
    win[k] = xs[ci * 1156 + (h + dy) * 34 + (w + dx)];
  }
  for (int cc = 0; cc < 16; ++cc) {  // 8 channels per chunk
    float y8[8];
#pragma unroll
    for (int j8 = 0; j8 < 8; ++j8) {
      const int c = cc * 8 + j8;
      const float* wp = w1f + c * 27;
      float acc = 0.0f;
#pragma unroll
      for (int k = 0; k < 27; ++k) acc = fmaf(wp[k], win[k], acc);
      float y = acc + cb[c];
      if (PASS) { const float d = y - st[2 * c]; y = d * d; }
      y8[j8] = y;
    }
    __syncthreads();  // previous chunk's readers done
#pragma unroll
    for (int j8 = 0; j8 < 8; ++j8) yl[t * 8 + j8] = y8[j8];
    __syncthreads();
    if (t < 128) {  // numpy 8-accumulator pass: r = sum_i y[i*8+j], i sequential
      const int L = t >> 6, j = (t >> 3) & 7, c8 = t & 7;
      float r = yl[(L * 128 + j) * 8 + c8];
      for (int i = 1; i < 16; ++i) r += yl[(L * 128 + i * 8 + j) * 8 + c8];
      rl[(L * 8 + c8) * 8 + j] = r;
    }
    __syncthreads();
    if (t < 16) {  // 8-way tree combine, write leaf sum
      const int L = t >> 3, c8 = t & 7;
      const float* p = rl + (L * 8 + c8) * 8;
      const float s =
          ((p[0] + p[1]) + (p[2] + p[3])) + ((p[4] + p[5]) + (p[6] + p[7]));
      BL[((size_t)(n * 8) + (q * 2 + L)) * 128 + (cc * 8 + c8)] = s;
    }
  }
}

// leaf-pairwise then batch-sequential combine (numpy multi-axis reduce order)
__global__ void conv1_comb2(const float* __restrict__ BL, float* __restrict__ st,
                            int pass) {
  const int c = threadIdx.x;  // 128
  if (c >= 128) return;
  float S = 0.0f;
  for (int n = 0; n < 256; ++n) {
    const float* L = BL + (size_t)n * 1024;
    const float l0 = L[0 * 128 + c], l1 = L[1 * 128 + c], l2 = L[2 * 128 + c],
                l3 = L[3 * 128 + c], l4 = L[4 * 128 + c], l5 = L[5 * 128 + c],
                l6 = L[6 * 128 + c], l7 = L[7 * 128 + c];
    const float Ln = ((l0 + l1) + (l2 + l3)) + ((l4 + l5) + (l6 + l7));
    S = (n == 0) ? Ln : (S + Ln);
  }
  if (pass == 0) st[2 * c] = S / 262144.0f;
  else           st[2 * c + 1] = 1.0f / sqrtf(S / 262144.0f + 1e-4f);
}

// binarize: thread = position; loops all 128 channels with register window,
// packs bits per-thread (bit l of word cq <-> c = cq*64+l).
__global__ void conv1_binz(const float* __restrict__ x,
                           const float* __restrict__ w1f,
                           const float* __restrict__ cb,
                           const float* __restrict__ st,
                           const float* __restrict__ g,
                           const float* __restrict__ be,
                           u64* __restrict__ out) {
  const int blk = blockIdx.x;  // n*4 + q
  const int n = blk >> 2, q = blk & 3;
  const int t = threadIdx.x;   // 256
  __shared__ float xs[3 * 34 * 34];
  stage_image(x, n, xs, 256, t);
  __syncthreads();
  const int hw = q * 256 + t;
  const int h = hw >> 5, w = hw & 31;
  float win[27];
#pragma unroll
  for (int k = 0; k < 27; ++k) {
    const int ci = k / 9, dy = (k % 9) / 3, dx = k % 3;
    win[k] = xs[ci * 1156 + (h + dy) * 34 + (w + dx)];
  }
  u64 m0 = 0, m1 = 0;
  for (int c = 0; c < 128; ++c) {
    const float* wp = w1f + c * 27;
    float acc = 0.0f;
#pragma unroll
    for (int k = 0; k < 27; ++k) acc = fmaf(wp[k], win[k], acc);
    const float y = acc + cb[c];
    const float tv = ((y - st[2 * c]) * st[2 * c + 1]) * g[c] + be[c];
    const u64 bit = (u64)bin01(tv);
    if (c < 64) m0 |= bit << c;
    else        m1 |= bit << (c - 64);
  }
  u64* dst = out + ((size_t)(n * 1024 + hw)) * 2;
  dst[0] = m0;
  dst[1] = m1;
}

// ===================== binary conv (+optional maxpool) =====================
// tap-major (R8): per tap, stage NE x QC cell-words in registers, reuse across
// NCPB channels; pc[NCPB][NE] persists. launch_bounds(256,4) ONLY - tighter
// bounds spill catastrophically (R7/R10 evidence).
template <int CQ, int POOL, int H, int COUT, int NCPB>
__launch_bounds__(256, 4)
__global__ void conv_bin(const u64* __restrict__ xin, const u64* __restrict__ wpk,
                         short* __restrict__ pre) {
  constexpr int OH = H / POOL;
  constexpr int PLANE = OH * OH;
  constexpr int G = 256 / PLANE;
  constexpr int NE = POOL * POOL;
  constexpr int NW_ = H * H * CQ;
  constexpr int QC = (CQ > 4) ? 4 : CQ;
  constexpr int NQC = CQ / QC;
  const int n = blockIdx.x;
  const int t = threadIdx.x;
  __shared__ u64 xs[NW_];
  const u64* src = xin + (size_t)n * NW_;
  for (int i = t; i < NW_; i += 256) xs[i] = src[i];
  __syncthreads();
  const int cosub = t / PLANE;
  const int pos = t % PLANE;
  const int oh = pos / OH, ow = pos % OH;

  int pc[NCPB][NE];
#pragma unroll
  for (int cc = 0; cc < NCPB; ++cc)
#pragma unroll
    for (int e = 0; e < NE; ++e) pc[cc][e] = 0;

#pragma unroll
  for (int qc = 0; qc < NQC; ++qc) {
#pragma unroll
    for (int k = 0; k < 9; ++k) {
      const int dy = k / 3, dx = k % 3;
      u64 cw[NE][QC];
      bool cv[NE];
#pragma unroll
      for (int py = 0; py < POOL; ++py) {
#pragma unroll
        for (int px = 0; px < POOL; ++px) {
          const int hh = oh * POOL + py + dy - 1;
          const int ww = ow * POOL + px + dx - 1;
          const bool v = ((unsigned)hh < (unsigned)H) && ((unsigned)ww < (unsigned)H);
          const int e = py * POOL + px;
          cv[e] = v;
          const int base = v ? ((hh * H + ww) * CQ + qc * QC) : 0;
#pragma unroll
          for (int q = 0; q < QC; ++q) cw[e][q] = xs[base + q];
        }
      }
#pragma unroll
      for (int cc = 0; cc < NCPB; ++cc) {
        const int co = (blockIdx.y * NCPB + cc) * G + cosub;
        const u64* wp = wpk + ((size_t)co * 9 + k) * CQ + qc * QC;
        u64 w[QC];
#pragma unroll
        for (int q = 0; q < QC; ++q) w[q] = wp[q];
#pragma unroll
        for (int e = 0; e < NE; ++e) {
          int tp = 0;
#pragma unroll
          for (int q = 0; q < QC; ++q) tp += __popcll(cw[e][q] ^ w[q]);
          pc[cc][e] += cv[e] ? tp : 0;
        }
      }
    }
  }

  int vcnt[NE];
#pragma unroll
  for (int py = 0; py < POOL; ++py) {
#pragma unroll
    for (int px = 0; px < POOL; ++px) {
      int cvn = 0;
#pragma unroll
      for (int dy = 0; dy < 3; ++dy)
#pragma unroll
        for (int dx = 0; dx < 3; ++dx) {
          const int hh = oh * POOL + py + dy - 1, ww = ow * POOL + px + dx - 1;
          cvn += (((unsigned)hh < (unsigned)H) && ((unsigned)ww < (unsigned)H)) ? 1 : 0;
        }
      vcnt[py * POOL + px] = cvn;
    }
  }
#pragma unroll
  for (int cc = 0; cc < NCPB; ++cc) {
    const int co = (blockIdx.y * NCPB + cc) * G + cosub;
    int best = -1000000;
#pragma unroll
    for (int e = 0; e < NE; ++e) {
      const int dot = vcnt[e] * (CQ * 64) - 2 * pc[cc][e];
      best = dot > best ? dot : best;
    }
    pre[((size_t)(n * COUT + co) * OH + oh) * OH + ow] = (short)best;
  }
}

// ======================= BN stats, numpy-faithful ==========================
template <int PASS>
__device__ __forceinline__ float acc8(const short* __restrict__ p, float b, float m,
                                      int start, int len) {
  float r[8];
#pragma unroll
  for (int j = 0; j < 8; ++j) {
    float y = (float)p[start + j] + b;
    if (PASS) { const float d = y - m; y = d * d; }
    r[j] = y;
  }
  for (int i = 8; i < len; i += 8) {
#pragma unroll
    for (int j = 0; j < 8; ++j) {
      float y = (float)p[start + i + j] + b;
      if (PASS) { const float d = y - m; y = d * d; }
      r[j] += y;
    }
  }
  return ((r[0] + r[1]) + (r[2] + r[3])) + ((r[4] + r[5]) + (r[6] + r[7]));
}

template <int PASS>
__device__ __forceinline__ float np_sum_hw(const short* __restrict__ p, float b,
                                           float m, int HW) {
  if (HW == 256) return acc8<PASS>(p, b, m, 0, 128) + acc8<PASS>(p, b, m, 128, 128);
  return acc8<PASS>(p, b, m, 0, HW);  // HW = 16 or 64
}

template <int HW>
__global__ void conv_stats(const short* __restrict__ pre, const float* __restrict__ cb,
                           float* __restrict__ st, int Cout) {
  const int c = blockIdx.x;
  const int n = threadIdx.x;  // 256
  const float b = cb[c];
  const short* p = pre + ((size_t)n * Cout + c) * HW;
  __shared__ float ls[256];
  ls[n] = np_sum_hw<0>(p, b, 0.0f, HW);
  __syncthreads();
  __shared__ float ms;
  if (n == 0) {
    float S = ls[0];
    for (int i = 1; i < 256; ++i) S += ls[i];
    ms = S / (float)(256 * HW);
  }
  __syncthreads();
  const float m = ms;
  __syncthreads();
  ls[n] = np_sum_hw<1>(p, b, m, HW);
  __syncthreads();
  if (n == 0) {
    float S = ls[0];
    for (int i = 1; i < 256; ++i) S += ls[i];
    const float v = S / (float)(256 * HW);
    st[2 * c] = m;
    st[2 * c + 1] = 1.0f / sqrtf(v + 1e-4f);
  }
}

// =========================== binarize 2d / pack ============================
// R10: lane = spatial position, loop channels, per-lane u64 assembly.
// Coalesced loads; same f32 expression, bit-map, addresses => bit-exact.
__global__ void bin2d(const short* __restrict__ pre, const float* __restrict__ st,
                      const float* __restrict__ cb, const float* __restrict__ g,
                      const float* __restrict__ be, u64* __restrict__ out,
                      int Cout, int OH) {
  const int CQ = Cout >> 6;
  const int HW = OH * OH;
  const int widx = blockIdx.x * 256 + threadIdx.x;  // (n*CQ+cq)*HW+hw
  const int hw = widx % HW;
  const int r = widx / HW;
  const int cq = r % CQ;
  const int n = r / CQ;
  const short* p = pre + ((size_t)(n * Cout + cq * 64)) * HW + hw;
  u64 mask = 0;
  for (int c = 0; c < 64; ++c) {
    const int ch = cq * 64 + c;
    const float val = (float)p[(size_t)c * HW] + cb[ch];
    const float tv = ((val - st[2 * ch]) * st[2 * ch + 1]) * g[ch] + be[ch];
    mask |= ((u64)bin01(tv)) << c;
  }
  out[((size_t)n * HW + hw) * CQ + cq] = mask;
}

// ================================ fc layers ================================
__global__ void fc_layer(const u64* __restrict__ xin, const u64* __restrict__ wpk,
                         short* __restrict__ pre, int FiQ, int Fo) {
  const int o = blockIdx.x;
  const int n = threadIdx.x;  // 256
  const u64* xp = xin + (size_t)n * FiQ;
  const u64* wp = wpk + (size_t)o * FiQ;
  int pc = 0;
  for (int q = 0; q < FiQ; ++q) pc += __popcll(xp[q] ^ wp[q]);
  pre[(size_t)n * Fo + o] = (short)(FiQ * 64 - 2 * pc);
}

__global__ void fc_stats(const short* __restrict__ pre, const float* __restrict__ fb,
                         float* __restrict__ st, int Fo) {
  const int o = blockIdx.x * 256 + threadIdx.x;
  if (o >= Fo) return;
  const float b = fb[o];
  float S = (float)pre[o] + b;
  for (int n = 1; n < 256; ++n) S += (float)pre[(size_t)n * Fo + o] + b;
  const float m = S / 256.0f;
  float d0 = (float)pre[o] + b - m;
  float V = d0 * d0;
  for (int n = 1; n < 256; ++n) {
    const float d = (float)pre[(size_t)n * Fo + o] + b - m;
    V += d * d;
  }
  st[2 * o] = m;
  st[2 * o + 1] = 1.0f / sqrtf(V / 256.0f + 1e-4f);
}

__global__ void fc_bin(const short* __restrict__ pre, const float* __restrict__ st,
                       const float* __restrict__ fb, const float* __restrict__ g,
                       const float* __restrict__ be, u64* __restrict__ out, int Fo) {
  const int gid = blockIdx.x * 4 + (threadIdx.x >> 6);
  const int lane = threadIdx.x & 63;
  const int OQ = Fo >> 6;
  const int oq = gid % OQ, n = gid / OQ;
  const int o = oq * 64 + lane;
  const float val = (float)pre[(size_t)n * Fo + o] + fb[o];
  const float tv = ((val - st[2 * o]) * st[2 * o + 1]) * g[o] + be[o];
  const u64 mask = __ballot(bin01(tv));
  if (lane == 0) out[(size_t)n * OQ + oq] = mask;
}

__global__ void fc_out(const short* __restrict__ pre, const float* __restrict__ st,
                       const float* __restrict__ fb, const float* __restrict__ g,
                       const float* __restrict__ be, float* __restrict__ out) {
  const int i = blockIdx.x * 256 + threadIdx.x;  // 2560
  if (i >= 2560) return;
  const int o = i % 10;
  const float val = (float)pre[i] + fb[o];
  out[i] = ((val - st[2 * o]) * st[2 * o + 1]) * g[o] + be[o];
}

// ================================= launch ==================================
extern "C" void kernel_launch(void* const* d_in, const int* in_sizes, int n_in,
                              void* d_out, int out_size, void* d_ws, size_t ws_size,
                              hipStream_t stream) {
  if (n_in < 37) return;
  const float* x = (const float*)d_in[0];
  const float *cw1 = (const float*)d_in[1],  *cb1 = (const float*)d_in[2],  *g1 = (const float*)d_in[3],  *be1 = (const float*)d_in[4];
  const float *cw2 = (const float*)d_in[5],  *cb2 = (const float*)d_in[6],  *g2 = (const float*)d_in[7],  *be2 = (const float*)d_in[8];
  const float *cw3 = (const float*)d_in[9],  *cb3 = (const float*)d_in[10], *g3 = (const float*)d_in[11], *be3 = (const float*)d_in[12];
  const float *cw4 = (const float*)d_in[13], *cb4 = (const float*)d_in[14], *g4 = (const float*)d_in[15], *be4 = (const float*)d_in[16];
  const float *cw5 = (const float*)d_in[17], *cb5 = (const float*)d_in[18], *g5 = (const float*)d_in[19], *be5 = (const float*)d_in[20];
  const float *cw6 = (const float*)d_in[21], *cb6 = (const float*)d_in[22], *g6 = (const float*)d_in[23], *be6 = (const float*)d_in[24];
  const float *fw1 = (const float*)d_in[25], *fb1 = (const float*)d_in[26], *gf1 = (const float*)d_in[27], *bef1 = (const float*)d_in[28];
  const float *fw2 = (const float*)d_in[29], *fb2 = (const float*)d_in[30], *gf2 = (const float*)d_in[31], *bef2 = (const float*)d_in[32];
  const float *fw3 = (const float*)d_in[33], *fb3 = (const float*)d_in[34], *gf3 = (const float*)d_in[35], *bef3 = (const float*)d_in[36];
  float* out = (float*)d_out;

  char* ws = (char*)d_ws;
  if (ws_size < 46137344) return;
  float* ST = (float*)ws;                    // f32 stats (m, 1/sqrt(v+eps)) pairs
  float* W1F = (float*)(ws + 32768);         // conv1 +-1.0f signs, 13824 B
  float* BL = (float*)(ws + 65536);          // conv1 leaf partials [256][8][128], 1 MB
  u64* W = (u64*)(ws + 1179648);             // packed weights, 1752320 B
  u64* A = (u64*)(ws + 2981888);             // packed activations, 9240576 B
  short* PRE = (short*)(ws + 12582912);      // integer pre-activations (reused)
  const int S1 = 0, S2 = 256, S3 = 512, S4 = 1024, S5 = 1536, S6 = 2560;
  const int SF1 = 3584, SF2 = 5632, SF3 = 7680;
  const size_t WC2 = 0, WC3 = 2304, WC4 = 6912, WC5 = 16128, WC6 = 34560;
  const size_t WF1 = 71424, WF2 = 202496, WF3 = 218880;
  const size_t A1 = 0, A2 = 524288, A3 = 655360, A4 = 917504, A5 = 983040;
  const size_t A6 = 1114112, AF1 = 1146880, AF2 = 1150976;

  // pack weights (literal bin_w semantics)
  pack_w1f<<<14, 256, 0, stream>>>(cw1, W1F);
  pack_conv_w<<<9, 256, 0, stream>>>(cw2, W + WC2, 128, 128);
  pack_conv_w<<<18, 256, 0, stream>>>(cw3, W + WC3, 256, 128);
  pack_conv_w<<<36, 256, 0, stream>>>(cw4, W + WC4, 256, 256);
  pack_conv_w<<<72, 256, 0, stream>>>(cw5, W + WC5, 512, 256);
  pack_conv_w<<<144, 256, 0, stream>>>(cw6, W + WC6, 512, 512);
  pack_fc1_w<<<512, 256, 0, stream>>>(fw1, W + WF1);
  pack_fc_w<<<64, 256, 0, stream>>>(fw2, W + WF2, 1024, 1024);
  pack_fc_w<<<1, 256, 0, stream>>>(fw3, W + WF3, 1024, 10);

  // layer 1: position-major f32 conv, numpy-faithful stats, binarize
  conv1_eval<0><<<1024, 256, 0, stream>>>(x, W1F, cb1, ST + S1, BL);
  conv1_comb2<<<1, 128, 0, stream>>>(BL, ST + S1, 0);
  conv1_eval<1><<<1024, 256, 0, stream>>>(x, W1F, cb1, ST + S1, BL);
  conv1_comb2<<<1, 128, 0, stream>>>(BL, ST + S1, 1);
  conv1_binz<<<1024, 256, 0, stream>>>(x, W1F, cb1, ST + S1, g1, be1, A + A1);

  // binary conv stack (tap-major, channel-split grids, NW=4 everywhere)
  conv_bin<2, 2, 32, 128, 4><<<dim3(256, 32), 256, 0, stream>>>(A + A1, W + WC2, PRE);
  conv_stats<256><<<128, 256, 0, stream>>>(PRE, cb2, ST + S2, 128);
  bin2d<<<512, 256, 0, stream>>>(PRE, ST + S2, cb2, g2, be2, A + A2, 128, 16);

  conv_bin<2, 1, 16, 256, 8><<<dim3(256, 32), 256, 0, stream>>>(A + A2, W + WC3, PRE);
  conv_stats<256><<<256, 256, 0, stream>>>(PRE, cb3, ST + S3, 256);
  bin2d<<<1024, 256, 0, stream>>>(PRE, ST + S3, cb3, g3, be3, A + A3, 256, 16);

  conv_bin<4, 2, 16, 256, 4><<<dim3(256, 16), 256, 0, stream>>>(A + A3, W + WC4, PRE);
  conv_stats<64><<<256, 256, 0, stream>>>(PRE, cb4, ST + S4, 256);
  bin2d<<<256, 256, 0, stream>>>(PRE, ST + S4, cb4, g4, be4, A + A4, 256, 8);

  conv_bin<4, 1, 8, 512, 8><<<dim3(256, 16), 256, 0, stream>>>(A + A4, W + WC5, PRE);
  conv_stats<64><<<512, 256, 0, stream>>>(PRE, cb5, ST + S5, 512);
  bin2d<<<512, 256, 0, stream>>>(PRE, ST + S5, cb5, g5, be5, A + A5, 512, 8);

  conv_bin<8, 2, 8, 512, 2><<<dim3(256, 16), 256, 0, stream>>>(A + A5, W + WC6, PRE);
  conv_stats<16><<<512, 256, 0, stream>>>(PRE, cb6, ST + S6, 512);
  bin2d<<<128, 256, 0, stream>>>(PRE, ST + S6, cb6, g6, be6, A + A6, 512, 4);

  // fc stack
  fc_layer<<<1024, 256, 0, stream>>>(A + A6, W + WF1, PRE, 128, 1024);
  fc_stats<<<4, 256, 0, stream>>>(PRE, fb1, ST + SF1, 1024);
  fc_bin<<<1024, 256, 0, stream>>>(PRE, ST + SF1, fb1, gf1, bef1, A + AF1, 1024);

  fc_layer<<<1024, 256, 0, stream>>>(A + AF1, W + WF2, PRE, 16, 1024);
  fc_stats<<<4, 256, 0, stream>>>(PRE, fb2, ST + SF2, 1024);
  fc_bin<<<1024, 256, 0, stream>>>(PRE, ST + SF2, fb2, gf2, bef2, A + AF2, 1024);

  fc_layer<<<10, 256, 0, stream>>>(A + AF2, W + WF3, PRE, 16, 10);
  fc_stats<<<1, 256, 0, stream>>>(PRE, fb3, ST + SF3, 10);
  fc_out<<<10, 256, 0, stream>>>(PRE, ST + SF3, fb3, gf3, bef3, out);
}